// Round 5
// baseline (628.122 us; speedup 1.0000x reference)
//
#include <hip/hip_runtime.h>
#include <hip/hip_bf16.h>

// fp32 inputs (confirmed). Internal pipeline bf16 MFMA.
// P trick: w = e>0 ? exp(e) : exp(0.2e), e=src_i+dst_j
//        = (B_j > T_i) ? A_i*B_j : C_i*D_j ; A=2^s, C=2^.2s, T=2^-s, B=2^d, D=2^.2d.

typedef unsigned short ushort_t;
typedef __attribute__((ext_vector_type(8))) short bf16x8;
typedef __attribute__((ext_vector_type(4))) float f32x4;
typedef __attribute__((ext_vector_type(16))) float f32x16;

#define LOG2E 1.4426950408889634f

__device__ __forceinline__ ushort_t f2bf(float x) {
    unsigned u = __builtin_bit_cast(unsigned, x);
    u += 0x7FFFu + ((u >> 16) & 1u);   // RNE
    return (ushort_t)(u >> 16);
}

// ---------------- kernel 1: WT[c][k] = W[k][c], 512x512, fp32 -> bf16 ----------------
__global__ __launch_bounds__(256) void transpose_w(const float* __restrict__ W,
                                                   ushort_t* __restrict__ WT) {
    __shared__ ushort_t t[32][33];
    int bx = blockIdx.x & 15, by = blockIdx.x >> 4;
    int tx = threadIdx.x & 31, ty = threadIdx.x >> 5;
#pragma unroll
    for (int i = 0; i < 32; i += 8)
        t[ty + i][tx] = f2bf(W[(by * 32 + ty + i) * 512 + bx * 32 + tx]);
    __syncthreads();
#pragma unroll
    for (int i = 0; i < 32; i += 8)
        WT[(bx * 32 + ty + i) * 512 + by * 32 + tx] = t[tx][ty + i];
}

// ---------------- kernel 2: WhT = WT @ h^T (LDS-staged, round-3 body) + exp epilogue --
__global__ __launch_bounds__(256) void gemm_whT(const ushort_t* __restrict__ WT,
                                                const float* __restrict__ h,
                                                const float* __restrict__ a,
                                                ushort_t* __restrict__ WhT,
                                                float* __restrict__ expA,
                                                float* __restrict__ expC,
                                                float* __restrict__ expT,
                                                float* __restrict__ expB,
                                                float* __restrict__ expD) {
    __shared__ ushort_t Al[64][40];
    __shared__ ushort_t Bl[64][40];
    __shared__ float asrc[64], adst[64];
    __shared__ float sred[2][4][64];
    int tid = threadIdx.x;
    int wave = tid >> 6, lane = tid & 63, quad = lane >> 4, nn = lane & 15;
    int mb = blockIdx.x & 7, nb = blockIdx.x >> 3;
    if (tid < 64) {
        asrc[tid] = a[tid] * LOG2E;
        adst[tid] = a[64 + tid] * LOG2E;
    }
    int r = tid >> 2, part = tid & 3;
    const ushort_t* Ag = WT + (unsigned)((mb * 64 + r) * 512 + part * 8);
    const float* Bg = h + (unsigned)((nb * 64 + r) * 512 + part * 8);
    f32x4 acc[4] = {};
    for (int kb = 0; kb < 512; kb += 32) {
        __syncthreads();
        *(bf16x8*)&Al[r][part * 8] = *(const bf16x8*)(Ag + kb);
        float4 f0 = *(const float4*)(Bg + kb);
        float4 f1 = *(const float4*)(Bg + kb + 4);
        bf16x8 bvv;
        bvv[0] = (short)f2bf(f0.x); bvv[1] = (short)f2bf(f0.y);
        bvv[2] = (short)f2bf(f0.z); bvv[3] = (short)f2bf(f0.w);
        bvv[4] = (short)f2bf(f1.x); bvv[5] = (short)f2bf(f1.y);
        bvv[6] = (short)f2bf(f1.z); bvv[7] = (short)f2bf(f1.w);
        *(bf16x8*)&Bl[r][part * 8] = bvv;
        __syncthreads();
        bf16x8 af = *(const bf16x8*)&Al[wave * 16 + nn][quad * 8];
#pragma unroll
        for (int nt = 0; nt < 4; nt++) {
            bf16x8 bv = *(const bf16x8*)&Bl[nt * 16 + nn][quad * 8];
            acc[nt] = __builtin_amdgcn_mfma_f32_16x16x32_bf16(af, bv, acc[nt], 0, 0, 0);
        }
    }
    int row0 = mb * 64 + wave * 16 + quad * 4;
    int col0 = nb * 64 + nn;
    int f0i = wave * 16 + quad * 4;
#pragma unroll
    for (int nt = 0; nt < 4; nt++) {
        float s = 0.f, d = 0.f;
#pragma unroll
        for (int rr = 0; rr < 4; rr++) {
            float v = acc[nt][rr];
            WhT[(unsigned)((row0 + rr) * 4096 + col0 + nt * 16)] = f2bf(v);
            s += v * asrc[f0i + rr];
            d += v * adst[f0i + rr];
        }
        s += __shfl_xor(s, 16); s += __shfl_xor(s, 32);
        d += __shfl_xor(d, 16); d += __shfl_xor(d, 32);
        if (quad == 0) { sred[0][wave][nt * 16 + nn] = s; sred[1][wave][nt * 16 + nn] = d; }
    }
    __syncthreads();
    if (tid < 64) {
        float s = sred[0][0][tid] + sred[0][1][tid] + sred[0][2][tid] + sred[0][3][tid];
        unsigned idx = mb * 4096 + nb * 64 + tid;
        expA[idx] = __builtin_amdgcn_exp2f(s);
        expC[idx] = __builtin_amdgcn_exp2f(0.2f * s);
        expT[idx] = __builtin_amdgcn_exp2f(-s);
    } else if (tid < 128) {
        int c = tid - 64;
        float d = sred[1][0][c] + sred[1][1][c] + sred[1][2][c] + sred[1][3][c];
        unsigned idx = mb * 4096 + nb * 64 + c;
        expB[idx] = __builtin_amdgcn_exp2f(d);
        expD[idx] = __builtin_amdgcn_exp2f(0.2f * d);
    }
}

// ---------------- kernel 3: fused masked-softmax attention + P@V + ELU ----------------
// 512 blocks x 512 thr, 3 blocks/CU. i-tile 32 x 2 heads; j-tile 64; dbuf; 1 barrier/iter.
// P@V via mfma 32x32x16 (waves 0-3). XOR-swizzled LDS (seg ^= row&7): conflict-free.
// hb = bid>>7 -> the 4 blocks sharing an adj row-band land on one XCD (L2 reuse).
__global__ __launch_bounds__(512, 6) void gat_attn(const int* __restrict__ adj,
                                                   const ushort_t* __restrict__ WhT,
                                                   const float* __restrict__ expA,
                                                   const float* __restrict__ expC,
                                                   const float* __restrict__ expT,
                                                   const float* __restrict__ expB,
                                                   const float* __restrict__ expD,
                                                   float* __restrict__ out) {
    __shared__ __align__(16) ushort_t Vb[2][128][64];     // 32 KB
    __shared__ __align__(16) ushort_t Pb[2][2][32][64];   // 16 KB
    __shared__ float denoml[2][32];
    int tid = threadIdx.x;
    int wave = tid >> 6, lane = tid & 63;
    int hb = blockIdx.x >> 7, ib = blockIdx.x & 127;
    int i0 = ib * 32;
    // gen role: (hh, pi, jo): 8 consecutive j per thread per iter
    int hh = tid >> 8;
    int pi = (tid >> 3) & 31, jo = tid & 7;
    int head = hb * 2 + hh;
    float Ai = expA[head * 4096 + i0 + pi];
    float Ci = expC[head * 4096 + i0 + pi];
    float Ti = expT[head * 4096 + i0 + pi];
    const int* adjP = adj + (unsigned)(i0 + pi) * 4096 + jo * 8;
    const float* Bp = expB + (unsigned)head * 4096 + jo * 8;
    const float* Dp = expD + (unsigned)head * 4096 + jo * 8;
    int psw = (jo ^ (pi & 7)) << 3;
    // V staging role: rows vr, vr+64; 16B col-seg vcs
    int vr = tid >> 3, vcs = tid & 7;
    const ushort_t* Vg0 = WhT + (unsigned)(hb * 128 + vr) * 4096 + vcs * 8;
    const ushort_t* Vg1 = Vg0 + (unsigned)64 * 4096;
    int vsw = (vcs ^ (vr & 7)) << 3;
    // MFMA role (waves 0-3): whead x nhalf; m=32 (all i), n=32 (f-half), K=64
    int whead = wave & 1, nhalf = (wave >> 1) & 1;
    int mrow = lane & 31, kh = lane >> 5;
    f32x16 acc = {};
    float dpart = 0.f;
    // prologue: prefetch tile 0
    int4 pa0 = *(const int4*)(adjP);
    int4 pa1 = *(const int4*)(adjP + 4);
    float4 pB0 = *(const float4*)(Bp);
    float4 pB1 = *(const float4*)(Bp + 4);
    float4 pD0 = *(const float4*)(Dp);
    float4 pD1 = *(const float4*)(Dp + 4);
    bf16x8 pv0 = *(const bf16x8*)(Vg0);
    bf16x8 pv1 = *(const bf16x8*)(Vg1);
#pragma unroll 2
    for (int k = 0; k < 64; k++) {
        int cb = k & 1;
        // ---- gen tile k from prefetched regs ----
        unsigned w0, w1, w2, w3, w4, w5, w6, w7;
        {
            float s1, s2, w;
            s1 = pB0.x > Ti ? pB0.x : pD0.x;  s2 = pB0.x > Ti ? Ai : Ci;  w = s1 * s2;
            w0 = __builtin_bit_cast(unsigned, w) & 0xFFFF0000u;  w0 = pa0.x > 0 ? w0 : 0u;
            s1 = pB0.y > Ti ? pB0.y : pD0.y;  s2 = pB0.y > Ti ? Ai : Ci;  w = s1 * s2;
            w1 = __builtin_bit_cast(unsigned, w) & 0xFFFF0000u;  w1 = pa0.y > 0 ? w1 : 0u;
            s1 = pB0.z > Ti ? pB0.z : pD0.z;  s2 = pB0.z > Ti ? Ai : Ci;  w = s1 * s2;
            w2 = __builtin_bit_cast(unsigned, w) & 0xFFFF0000u;  w2 = pa0.z > 0 ? w2 : 0u;
            s1 = pB0.w > Ti ? pB0.w : pD0.w;  s2 = pB0.w > Ti ? Ai : Ci;  w = s1 * s2;
            w3 = __builtin_bit_cast(unsigned, w) & 0xFFFF0000u;  w3 = pa0.w > 0 ? w3 : 0u;
            s1 = pB1.x > Ti ? pB1.x : pD1.x;  s2 = pB1.x > Ti ? Ai : Ci;  w = s1 * s2;
            w4 = __builtin_bit_cast(unsigned, w) & 0xFFFF0000u;  w4 = pa1.x > 0 ? w4 : 0u;
            s1 = pB1.y > Ti ? pB1.y : pD1.y;  s2 = pB1.y > Ti ? Ai : Ci;  w = s1 * s2;
            w5 = __builtin_bit_cast(unsigned, w) & 0xFFFF0000u;  w5 = pa1.y > 0 ? w5 : 0u;
            s1 = pB1.z > Ti ? pB1.z : pD1.z;  s2 = pB1.z > Ti ? Ai : Ci;  w = s1 * s2;
            w6 = __builtin_bit_cast(unsigned, w) & 0xFFFF0000u;  w6 = pa1.z > 0 ? w6 : 0u;
            s1 = pB1.w > Ti ? pB1.w : pD1.w;  s2 = pB1.w > Ti ? Ai : Ci;  w = s1 * s2;
            w7 = __builtin_bit_cast(unsigned, w) & 0xFFFF0000u;  w7 = pa1.w > 0 ? w7 : 0u;
        }
        dpart += __builtin_bit_cast(float, w0) + __builtin_bit_cast(float, w1)
               + __builtin_bit_cast(float, w2) + __builtin_bit_cast(float, w3)
               + __builtin_bit_cast(float, w4) + __builtin_bit_cast(float, w5)
               + __builtin_bit_cast(float, w6) + __builtin_bit_cast(float, w7);
        uint4 pq;
        pq.x = __builtin_amdgcn_perm(w1, w0, 0x07060302u);
        pq.y = __builtin_amdgcn_perm(w3, w2, 0x07060302u);
        pq.z = __builtin_amdgcn_perm(w5, w4, 0x07060302u);
        pq.w = __builtin_amdgcn_perm(w7, w6, 0x07060302u);
        *(uint4*)&Pb[cb][hh][pi][psw] = pq;
        *(bf16x8*)&Vb[cb][vr][vsw] = pv0;
        *(bf16x8*)&Vb[cb][64 + vr][vsw] = pv1;
        // ---- prefetch tile k+1 ----
        if (k < 63) {
            const int* ap = adjP + (k + 1) * 64;
            pa0 = *(const int4*)(ap);
            pa1 = *(const int4*)(ap + 4);
            pB0 = *(const float4*)(Bp + (k + 1) * 64);
            pB1 = *(const float4*)(Bp + (k + 1) * 64 + 4);
            pD0 = *(const float4*)(Dp + (k + 1) * 64);
            pD1 = *(const float4*)(Dp + (k + 1) * 64 + 4);
            pv0 = *(const bf16x8*)(Vg0 + (k + 1) * 64);
            pv1 = *(const bf16x8*)(Vg1 + (k + 1) * 64);
        }
        // ---- MFMA tile k-1 (waves 0-3) ----
        if (k > 0 && wave < 4) {
            int pbuf = cb ^ 1;
#pragma unroll
            for (int kk = 0; kk < 4; kk++) {
                int sw = (((kk << 1) | kh) ^ (mrow & 7)) << 3;
                bf16x8 af = *(const bf16x8*)&Pb[pbuf][whead][mrow][sw];
                bf16x8 bv = *(const bf16x8*)&Vb[pbuf][whead * 64 + nhalf * 32 + mrow][sw];
                acc = __builtin_amdgcn_mfma_f32_32x32x16_bf16(af, bv, acc, 0, 0, 0);
            }
        }
        __syncthreads();
    }
    // denominator reduce (all waves' gen lanes)
    float dsum = dpart;
    dsum += __shfl_xor(dsum, 1);
    dsum += __shfl_xor(dsum, 2);
    dsum += __shfl_xor(dsum, 4);
    if ((lane & 7) == 0) denoml[hh][pi] = dsum;
    // tail MFMA: tile 63 (buffer 1)
    if (wave < 4) {
#pragma unroll
        for (int kk = 0; kk < 4; kk++) {
            int sw = (((kk << 1) | kh) ^ (mrow & 7)) << 3;
            bf16x8 af = *(const bf16x8*)&Pb[1][whead][mrow][sw];
            bf16x8 bv = *(const bf16x8*)&Vb[1][whead * 64 + nhalf * 32 + mrow][sw];
            acc = __builtin_amdgcn_mfma_f32_32x32x16_bf16(af, bv, acc, 0, 0, 0);
        }
    }
    __syncthreads();
    // epilogue: C/D 32x32 layout: col=lane&31, row=(r&3)+8*(r>>2)+4*(lane>>5)
    if (wave < 4) {
#pragma unroll
        for (int r = 0; r < 16; r++) {
            int row = (r & 3) + ((r >> 2) << 3) + (kh << 2);
            float dnm = fmaxf(denoml[whead][row], 1e-30f);
            float v = acc[r] / dnm;
            v = v > 0.f ? v : __expf(v) - 1.f;
            out[(unsigned)(i0 + row) * 512 + (hb * 2 + whead) * 64 + nhalf * 32 + mrow] = v;
        }
    }
}

extern "C" void kernel_launch(void* const* d_in, const int* in_sizes, int n_in,
                              void* d_out, int out_size, void* d_ws, size_t ws_size,
                              hipStream_t stream) {
    const float* h   = (const float*)d_in[0];   // 4096 x 512 fp32
    const int*   adj = (const int*)d_in[1];     // 4096 x 4096 int32
    const float* W   = (const float*)d_in[2];   // 512 x 512 fp32
    const float* a   = (const float*)d_in[3];   // 128 fp32

    char* ws = (char*)d_ws;
    ushort_t* WhT = (ushort_t*)ws;                      // 4 MB
    ushort_t* WT  = (ushort_t*)(ws + (4u << 20));       // 512 KB
    float* expA = (float*)(ws + (4u << 20) + (512u << 10));  // 5 x 128 KB
    float* expC = expA + 8 * 4096;
    float* expT = expC + 8 * 4096;
    float* expB = expT + 8 * 4096;
    float* expD = expB + 8 * 4096;

    transpose_w<<<256, 256, 0, stream>>>(W, WT);
    gemm_whT<<<512, 256, 0, stream>>>(WT, h, a, WhT, expA, expC, expT, expB, expD);
    gat_attn<<<512, 512, 0, stream>>>(adj, WhT, expA, expC, expT, expB, expD,
                                      (float*)d_out);
}

// Round 7
// 200.666 us; speedup vs baseline: 3.1302x; 3.1302x over previous
//
#include <hip/hip_runtime.h>
#include <hip/hip_bf16.h>

// fp32 inputs (confirmed r2). Internal pipeline bf16 MFMA.
// Gen identity: w = exp2(max(e,0.2e)) = max(A_i*B_j, C_i*D_j);
//   A=2^s, C=2^0.2s (rows), B=2^d, D=2^0.2d (cols) -- exp2 monotone.
// r7 = round-3 proven structure + bottom-barrier fix (r3 had a tail race) +
//      factored-exp gen. Bisects r6's post-timing failure.

typedef unsigned short ushort_t;
typedef __attribute__((ext_vector_type(8))) short bf16x8;
typedef __attribute__((ext_vector_type(4))) float f32x4;

#define LOG2E 1.4426950408889634f

__device__ __forceinline__ ushort_t f2bf(float x) {
    unsigned u = __builtin_bit_cast(unsigned, x);
    u += 0x7FFFu + ((u >> 16) & 1u);   // RNE
    return (ushort_t)(u >> 16);
}

// ---------------- kernel 1: WT[c][k] = W[k][c], 512x512, fp32 -> bf16 ----------------
__global__ __launch_bounds__(256) void transpose_w(const float* __restrict__ W,
                                                   ushort_t* __restrict__ WT) {
    __shared__ ushort_t t[32][33];
    int bx = blockIdx.x & 15, by = blockIdx.x >> 4;
    int tx = threadIdx.x & 31, ty = threadIdx.x >> 5;
#pragma unroll
    for (int i = 0; i < 32; i += 8)
        t[ty + i][tx] = f2bf(W[(by * 32 + ty + i) * 512 + bx * 32 + tx]);
    __syncthreads();
#pragma unroll
    for (int i = 0; i < 32; i += 8)
        WT[(bx * 32 + ty + i) * 512 + by * 32 + tx] = t[tx][ty + i];
}

// -------- kernel 2: WhT = WT @ h^T (round-3 LDS-staged body) + exp epilogue --------
__global__ __launch_bounds__(256) void gemm_whT(const ushort_t* __restrict__ WT,
                                                const float* __restrict__ h,
                                                const float* __restrict__ a,
                                                ushort_t* __restrict__ WhT,
                                                float* __restrict__ expA,
                                                float* __restrict__ expC,
                                                float* __restrict__ expB,
                                                float* __restrict__ expD) {
    __shared__ ushort_t Al[64][40];
    __shared__ ushort_t Bl[64][40];
    __shared__ float asrc[64], adst[64];
    __shared__ float sred[2][4][64];
    int tid = threadIdx.x;
    int wave = tid >> 6, lane = tid & 63, quad = lane >> 4, nn = lane & 15;
    int mb = blockIdx.x & 7, nb = blockIdx.x >> 3;
    if (tid < 64) {
        asrc[tid] = a[tid] * LOG2E;
        adst[tid] = a[64 + tid] * LOG2E;
    }
    int r = tid >> 2, part = tid & 3;
    const ushort_t* Ag = WT + (unsigned)((mb * 64 + r) * 512 + part * 8);
    const float* Bg = h + (unsigned)((nb * 64 + r) * 512 + part * 8);
    f32x4 acc[4] = {};
    for (int kb = 0; kb < 512; kb += 32) {
        __syncthreads();
        *(bf16x8*)&Al[r][part * 8] = *(const bf16x8*)(Ag + kb);
        float4 f0 = *(const float4*)(Bg + kb);
        float4 f1 = *(const float4*)(Bg + kb + 4);
        bf16x8 bvv;
        bvv[0] = (short)f2bf(f0.x); bvv[1] = (short)f2bf(f0.y);
        bvv[2] = (short)f2bf(f0.z); bvv[3] = (short)f2bf(f0.w);
        bvv[4] = (short)f2bf(f1.x); bvv[5] = (short)f2bf(f1.y);
        bvv[6] = (short)f2bf(f1.z); bvv[7] = (short)f2bf(f1.w);
        *(bf16x8*)&Bl[r][part * 8] = bvv;
        __syncthreads();
        bf16x8 af = *(const bf16x8*)&Al[wave * 16 + nn][quad * 8];
#pragma unroll
        for (int nt = 0; nt < 4; nt++) {
            bf16x8 bv = *(const bf16x8*)&Bl[nt * 16 + nn][quad * 8];
            acc[nt] = __builtin_amdgcn_mfma_f32_16x16x32_bf16(af, bv, acc[nt], 0, 0, 0);
        }
    }
    int row0 = mb * 64 + wave * 16 + quad * 4;
    int col0 = nb * 64 + nn;
    int f0i = wave * 16 + quad * 4;
#pragma unroll
    for (int nt = 0; nt < 4; nt++) {
        float s = 0.f, d = 0.f;
#pragma unroll
        for (int rr = 0; rr < 4; rr++) {
            float v = acc[nt][rr];
            WhT[(unsigned)((row0 + rr) * 4096 + col0 + nt * 16)] = f2bf(v);
            s += v * asrc[f0i + rr];
            d += v * adst[f0i + rr];
        }
        s += __shfl_xor(s, 16); s += __shfl_xor(s, 32);
        d += __shfl_xor(d, 16); d += __shfl_xor(d, 32);
        if (quad == 0) { sred[0][wave][nt * 16 + nn] = s; sred[1][wave][nt * 16 + nn] = d; }
    }
    __syncthreads();
    if (tid < 64) {
        float s = sred[0][0][tid] + sred[0][1][tid] + sred[0][2][tid] + sred[0][3][tid];
        unsigned idx = mb * 4096 + nb * 64 + tid;
        expA[idx] = __builtin_amdgcn_exp2f(s);
        expC[idx] = __builtin_amdgcn_exp2f(0.2f * s);
    } else if (tid < 128) {
        int c = tid - 64;
        float d = sred[1][0][c] + sred[1][1][c] + sred[1][2][c] + sred[1][3][c];
        unsigned idx = mb * 4096 + nb * 64 + c;
        expB[idx] = __builtin_amdgcn_exp2f(d);
        expD[idx] = __builtin_amdgcn_exp2f(0.2f * d);
    }
}

// -------- kernel 3: fused masked-softmax attention + P@V + ELU (round-3 skeleton) ----
// 512 blocks x 512 thr, (512,4) = 2 blocks/CU. i-tile 32 x 2 heads; j-tile 64;
// dbuf LDS; ONE barrier per iter at loop BOTTOM (fixes r3's tail race).
// MFMA 16x16x32 on all 8 waves (jhalf split, combined via cmb overlay on Vb[0]).
__global__ __launch_bounds__(512, 4) void gat_attn(const int* __restrict__ adj,
                                                   const ushort_t* __restrict__ WhT,
                                                   const float* __restrict__ expA,
                                                   const float* __restrict__ expC,
                                                   const float* __restrict__ expB,
                                                   const float* __restrict__ expD,
                                                   float* __restrict__ out) {
    __shared__ __align__(16) ushort_t Vb[2][128][72];     // 36864 B
    __shared__ __align__(16) ushort_t Pb[2][2][32][72];   // 18432 B
    __shared__ float denoml[2][32];
    int tid = threadIdx.x;
    int wave = tid >> 6, lane = tid & 63, quad = lane >> 4, nn = lane & 15;
    int hb = blockIdx.x >> 7, ib = blockIdx.x & 127;   // adj row-band stays on one XCD
    int i0 = ib * 32;
    // gen role: (hh, pi, jo) -> 8 consecutive j per iter
    int hh = tid >> 8, tt = tid & 255;
    int pi = tt >> 3, jo = tt & 7;
    int head = hb * 2 + hh;
    float Ai = expA[head * 4096 + i0 + pi];
    float Ci = expC[head * 4096 + i0 + pi];
    const int* adjP = adj + (unsigned)(i0 + pi) * 4096 + jo * 8;
    const float* Bp = expB + (unsigned)head * 4096 + jo * 8;
    const float* Dp = expD + (unsigned)head * 4096 + jo * 8;
    // V staging role
    int vr = tid >> 3, vcs = tid & 7;
    const ushort_t* Vg0 = WhT + (unsigned)(hb * 128 + vr) * 4096 + vcs * 8;
    const ushort_t* Vg1 = Vg0 + 64u * 4096u;
    // MFMA role
    int jhalf = wave >> 2, ws = wave & 3;
    int strip = ws & 1, whead = ws >> 1;
    f32x4 acc[4] = {};
    float dpart = 0.f;
    // prologue: prefetch adj + V for tile 0 (B/D are L2-hot, loaded directly)
    int4 pa[2][2]; bf16x8 pvv[2][2];
    pa[0][0] = *(const int4*)(adjP);
    pa[0][1] = *(const int4*)(adjP + 4);
    pvv[0][0] = *(const bf16x8*)(Vg0);
    pvv[0][1] = *(const bf16x8*)(Vg1);
#pragma unroll 2
    for (int k = 0; k < 64; k++) {
        int cb = k & 1;
        // ---- gen tile k: w = max(Ai*B, Ci*D), masked, truncated to bf16 ----
        float4 Bv0 = *(const float4*)(Bp + k * 64);
        float4 Bv1 = *(const float4*)(Bp + k * 64 + 4);
        float4 Dv0 = *(const float4*)(Dp + k * 64);
        float4 Dv1 = *(const float4*)(Dp + k * 64 + 4);
        int4 a0 = pa[cb][0], a1 = pa[cb][1];
        unsigned w0, w1, w2, w3, w4, w5, w6, w7;
        {
            float w;
            w = fmaxf(Ai * Bv0.x, Ci * Dv0.x);
            w0 = __builtin_bit_cast(unsigned, w) & 0xFFFF0000u;  w0 = a0.x > 0 ? w0 : 0u;
            w = fmaxf(Ai * Bv0.y, Ci * Dv0.y);
            w1 = __builtin_bit_cast(unsigned, w) & 0xFFFF0000u;  w1 = a0.y > 0 ? w1 : 0u;
            w = fmaxf(Ai * Bv0.z, Ci * Dv0.z);
            w2 = __builtin_bit_cast(unsigned, w) & 0xFFFF0000u;  w2 = a0.z > 0 ? w2 : 0u;
            w = fmaxf(Ai * Bv0.w, Ci * Dv0.w);
            w3 = __builtin_bit_cast(unsigned, w) & 0xFFFF0000u;  w3 = a0.w > 0 ? w3 : 0u;
            w = fmaxf(Ai * Bv1.x, Ci * Dv1.x);
            w4 = __builtin_bit_cast(unsigned, w) & 0xFFFF0000u;  w4 = a1.x > 0 ? w4 : 0u;
            w = fmaxf(Ai * Bv1.y, Ci * Dv1.y);
            w5 = __builtin_bit_cast(unsigned, w) & 0xFFFF0000u;  w5 = a1.y > 0 ? w5 : 0u;
            w = fmaxf(Ai * Bv1.z, Ci * Dv1.z);
            w6 = __builtin_bit_cast(unsigned, w) & 0xFFFF0000u;  w6 = a1.z > 0 ? w6 : 0u;
            w = fmaxf(Ai * Bv1.w, Ci * Dv1.w);
            w7 = __builtin_bit_cast(unsigned, w) & 0xFFFF0000u;  w7 = a1.w > 0 ? w7 : 0u;
        }
        dpart += __builtin_bit_cast(float, w0) + __builtin_bit_cast(float, w1)
               + __builtin_bit_cast(float, w2) + __builtin_bit_cast(float, w3)
               + __builtin_bit_cast(float, w4) + __builtin_bit_cast(float, w5)
               + __builtin_bit_cast(float, w6) + __builtin_bit_cast(float, w7);
        uint4 pq;
        pq.x = __builtin_amdgcn_perm(w1, w0, 0x07060302u);
        pq.y = __builtin_amdgcn_perm(w3, w2, 0x07060302u);
        pq.z = __builtin_amdgcn_perm(w5, w4, 0x07060302u);
        pq.w = __builtin_amdgcn_perm(w7, w6, 0x07060302u);
        *(uint4*)&Pb[cb][hh][pi][jo * 8] = pq;
        *(bf16x8*)&Vb[cb][vr][vcs * 8] = pvv[cb][0];
        *(bf16x8*)&Vb[cb][64 + vr][vcs * 8] = pvv[cb][1];
        // ---- prefetch adj + V for tile k+1 ----
        if (k < 63) {
            const int* ap = adjP + (k + 1) * 64;
            pa[cb ^ 1][0] = *(const int4*)(ap);
            pa[cb ^ 1][1] = *(const int4*)(ap + 4);
            pvv[cb ^ 1][0] = *(const bf16x8*)(Vg0 + (k + 1) * 64);
            pvv[cb ^ 1][1] = *(const bf16x8*)(Vg1 + (k + 1) * 64);
        }
        // ---- MFMA tile k-1 from the other buffer ----
        if (k > 0) {
            int pbuf = cb ^ 1;
            bf16x8 af = *(const bf16x8*)&Pb[pbuf][whead][strip * 16 + nn][jhalf * 32 + quad * 8];
#pragma unroll
            for (int nt = 0; nt < 4; nt++) {
                bf16x8 bv = *(const bf16x8*)&Vb[pbuf][whead * 64 + nt * 16 + nn][jhalf * 32 + quad * 8];
                acc[nt] = __builtin_amdgcn_mfma_f32_16x16x32_bf16(af, bv, acc[nt], 0, 0, 0);
            }
        }
        __syncthreads();   // BOTTOM barrier: protects next-iter overwrite AND the tail
    }
    {   // tail: mfma tile 63 (buffer 1) -- k=63 stores drained by loop-end barrier
        bf16x8 af = *(const bf16x8*)&Pb[1][whead][strip * 16 + nn][jhalf * 32 + quad * 8];
#pragma unroll
        for (int nt = 0; nt < 4; nt++) {
            bf16x8 bv = *(const bf16x8*)&Vb[1][whead * 64 + nt * 16 + nn][jhalf * 32 + quad * 8];
            acc[nt] = __builtin_amdgcn_mfma_f32_16x16x32_bf16(af, bv, acc[nt], 0, 0, 0);
        }
    }
    // denominator: reduce over jo (8 consecutive lanes)
    float dsum = dpart;
    dsum += __shfl_xor(dsum, 1);
    dsum += __shfl_xor(dsum, 2);
    dsum += __shfl_xor(dsum, 4);
    if ((tid & 7) == 0) denoml[hh][pi] = dsum;
    __syncthreads();   // denoml visible; tail Vb[1] reads done (cmb overlays Vb[0])
    // combine jhalf partials via LDS overlay on Vb[0] slab
    float (*cmb)[64][8] = reinterpret_cast<float (*)[64][8]>(&Vb[0][0][0]);
    if (jhalf == 1) {
        *(f32x4*)&cmb[ws][lane][0] = acc[0] ;
        *(f32x4*)&cmb[ws][lane][4] = acc[1];
        // store acc[2], acc[3] after barrier? no -- pack all 16 floats: use two rows
    }
    __syncthreads();
    if (jhalf == 0) {
        f32x4 o0 = acc[0] + *(const f32x4*)&cmb[ws][lane][0];
        f32x4 o1 = acc[1] + *(const f32x4*)&cmb[ws][lane][4];
#pragma unroll
        for (int rr = 0; rr < 4; rr++) {
            int il = strip * 16 + quad * 4 + rr;
            float dnm = fmaxf(denoml[whead][il], 1e-30f);
            float v0 = o0[rr] / dnm;
            float v1 = o1[rr] / dnm;
            v0 = v0 > 0.f ? v0 : __expf(v0) - 1.f;
            v1 = v1 > 0.f ? v1 : __expf(v1) - 1.f;
            unsigned oi = (unsigned)(i0 + il) * 512 + hb * 128 + whead * 64 + nn;
            out[oi] = v0;
            out[oi + 16] = v1;
        }
    }
    __syncthreads();
    // second half: nt = 2,3 (reuse the same cmb slab)
    if (jhalf == 1) {
        *(f32x4*)&cmb[ws][lane][0] = acc[2];
        *(f32x4*)&cmb[ws][lane][4] = acc[3];
    }
    __syncthreads();
    if (jhalf == 0) {
        f32x4 o0 = acc[2] + *(const f32x4*)&cmb[ws][lane][0];
        f32x4 o1 = acc[3] + *(const f32x4*)&cmb[ws][lane][4];
#pragma unroll
        for (int rr = 0; rr < 4; rr++) {
            int il = strip * 16 + quad * 4 + rr;
            float dnm = fmaxf(denoml[whead][il], 1e-30f);
            float v0 = o0[rr] / dnm;
            float v1 = o1[rr] / dnm;
            v0 = v0 > 0.f ? v0 : __expf(v0) - 1.f;
            v1 = v1 > 0.f ? v1 : __expf(v1) - 1.f;
            unsigned oi = (unsigned)(i0 + il) * 512 + hb * 128 + whead * 64 + 32 + nn;
            out[oi] = v0;
            out[oi + 16] = v1;
        }
    }
}

extern "C" void kernel_launch(void* const* d_in, const int* in_sizes, int n_in,
                              void* d_out, int out_size, void* d_ws, size_t ws_size,
                              hipStream_t stream) {
    const float* h   = (const float*)d_in[0];   // 4096 x 512 fp32
    const int*   adj = (const int*)d_in[1];     // 4096 x 4096 int32
    const float* W   = (const float*)d_in[2];   // 512 x 512 fp32
    const float* a   = (const float*)d_in[3];   // 128 fp32

    char* ws = (char*)d_ws;
    ushort_t* WhT = (ushort_t*)ws;                      // 4 MB
    ushort_t* WT  = (ushort_t*)(ws + (4u << 20));       // 512 KB
    float* expA = (float*)(ws + (4u << 20) + (512u << 10));  // 4 x 128 KB
    float* expC = expA + 8 * 4096;
    float* expB = expC + 8 * 4096;
    float* expD = expB + 8 * 4096;

    transpose_w<<<256, 256, 0, stream>>>(W, WT);
    gemm_whT<<<512, 256, 0, stream>>>(WT, h, a, WhT, expA, expC, expB, expD);
    gat_attn<<<512, 512, 0, stream>>>(adj, WhT, expA, expC, expB, expD,
                                      (float*)d_out);
}

// Round 8
// 191.382 us; speedup vs baseline: 3.2820x; 1.0485x over previous
//
#include <hip/hip_runtime.h>
#include <hip/hip_bf16.h>

// fp32 inputs (confirmed r2). Internal pipeline bf16 MFMA.
// Gen identity: w = exp2(max(e,0.2e)) = max(A_i*B_j, C_i*D_j);
//   A=2^s, C=2^0.2s (rows), B=2^d, D=2^0.2d (cols) -- exp2 monotone.
// r8 = r7 + pipelined gemm (BK=64, dbuf, reg-prefetch, 1 bottom barrier/iter)
//      + expB/expD register prefetch in attn. r6's failed bundle avoided.

typedef unsigned short ushort_t;
typedef __attribute__((ext_vector_type(8))) short bf16x8;
typedef __attribute__((ext_vector_type(4))) float f32x4;

#define LOG2E 1.4426950408889634f

__device__ __forceinline__ ushort_t f2bf(float x) {
    unsigned u = __builtin_bit_cast(unsigned, x);
    u += 0x7FFFu + ((u >> 16) & 1u);   // RNE
    return (ushort_t)(u >> 16);
}

// ---------------- kernel 1: WT[c][k] = W[k][c], 512x512, fp32 -> bf16 ----------------
__global__ __launch_bounds__(256) void transpose_w(const float* __restrict__ W,
                                                   ushort_t* __restrict__ WT) {
    __shared__ ushort_t t[32][33];
    int bx = blockIdx.x & 15, by = blockIdx.x >> 4;
    int tx = threadIdx.x & 31, ty = threadIdx.x >> 5;
#pragma unroll
    for (int i = 0; i < 32; i += 8)
        t[ty + i][tx] = f2bf(W[(by * 32 + ty + i) * 512 + bx * 32 + tx]);
    __syncthreads();
#pragma unroll
    for (int i = 0; i < 32; i += 8)
        WT[(bx * 32 + ty + i) * 512 + by * 32 + tx] = t[tx][ty + i];
}

// -------- kernel 2: WhT = WT @ h^T, pipelined (BK=64, dbuf, 1 barrier/iter) --------
// Block = 64c x 64n. Staging: row r=tid>>2, segs s0=tid&3 and s0+4 (8 elems each).
// MFMA/epilogue fragment math identical to proven r7.
__global__ __launch_bounds__(256, 4) void gemm_whT(const ushort_t* __restrict__ WT,
                                                   const float* __restrict__ h,
                                                   const float* __restrict__ a,
                                                   ushort_t* __restrict__ WhT,
                                                   float* __restrict__ expA,
                                                   float* __restrict__ expC,
                                                   float* __restrict__ expB,
                                                   float* __restrict__ expD) {
    __shared__ __align__(16) ushort_t Al[2][64][72];   // 18432 B
    __shared__ __align__(16) ushort_t Bl[2][64][72];   // 18432 B
    __shared__ float asrc[64], adst[64];
    __shared__ float sred[2][4][64];
    int tid = threadIdx.x;
    int wave = tid >> 6, lane = tid & 63, quad = lane >> 4, nn = lane & 15;
    int mb = blockIdx.x & 7, nb = blockIdx.x >> 3;
    if (tid < 64) {
        asrc[tid] = a[tid] * LOG2E;
        adst[tid] = a[64 + tid] * LOG2E;
    }
    int r = tid >> 2, s0 = tid & 3;
    const ushort_t* Ag = WT + (unsigned)((mb * 64 + r) * 512 + s0 * 8);
    const float* Bg = h + (unsigned)((nb * 64 + r) * 512 + s0 * 8);
    // prologue: prefetch tile 0
    bf16x8 pA0 = *(const bf16x8*)(Ag);
    bf16x8 pA1 = *(const bf16x8*)(Ag + 32);
    float4 pb0 = *(const float4*)(Bg);
    float4 pb1 = *(const float4*)(Bg + 4);
    float4 pb2 = *(const float4*)(Bg + 32);
    float4 pb3 = *(const float4*)(Bg + 36);
    f32x4 acc[4] = {};
#pragma unroll 2
    for (int t = 0; t < 8; t++) {
        int cb = t & 1;
        // store tile t
        *(bf16x8*)&Al[cb][r][s0 * 8] = pA0;
        *(bf16x8*)&Al[cb][r][s0 * 8 + 32] = pA1;
        bf16x8 bv;
        bv[0] = (short)f2bf(pb0.x); bv[1] = (short)f2bf(pb0.y);
        bv[2] = (short)f2bf(pb0.z); bv[3] = (short)f2bf(pb0.w);
        bv[4] = (short)f2bf(pb1.x); bv[5] = (short)f2bf(pb1.y);
        bv[6] = (short)f2bf(pb1.z); bv[7] = (short)f2bf(pb1.w);
        *(bf16x8*)&Bl[cb][r][s0 * 8] = bv;
        bv[0] = (short)f2bf(pb2.x); bv[1] = (short)f2bf(pb2.y);
        bv[2] = (short)f2bf(pb2.z); bv[3] = (short)f2bf(pb2.w);
        bv[4] = (short)f2bf(pb3.x); bv[5] = (short)f2bf(pb3.y);
        bv[6] = (short)f2bf(pb3.z); bv[7] = (short)f2bf(pb3.w);
        *(bf16x8*)&Bl[cb][r][s0 * 8 + 32] = bv;
        // prefetch tile t+1
        if (t < 7) {
            int ko = (t + 1) * 64;
            pA0 = *(const bf16x8*)(Ag + ko);
            pA1 = *(const bf16x8*)(Ag + ko + 32);
            pb0 = *(const float4*)(Bg + ko);
            pb1 = *(const float4*)(Bg + ko + 4);
            pb2 = *(const float4*)(Bg + ko + 32);
            pb3 = *(const float4*)(Bg + ko + 36);
        }
        // MFMA tile t-1 from other buffer
        if (t > 0) {
            int pb = cb ^ 1;
            bf16x8 af0 = *(const bf16x8*)&Al[pb][wave * 16 + nn][quad * 8];
            bf16x8 af1 = *(const bf16x8*)&Al[pb][wave * 16 + nn][32 + quad * 8];
#pragma unroll
            for (int nt = 0; nt < 4; nt++) {
                bf16x8 b0 = *(const bf16x8*)&Bl[pb][nt * 16 + nn][quad * 8];
                bf16x8 b1 = *(const bf16x8*)&Bl[pb][nt * 16 + nn][32 + quad * 8];
                acc[nt] = __builtin_amdgcn_mfma_f32_16x16x32_bf16(af0, b0, acc[nt], 0, 0, 0);
                acc[nt] = __builtin_amdgcn_mfma_f32_16x16x32_bf16(af1, b1, acc[nt], 0, 0, 0);
            }
        }
        __syncthreads();
    }
    {   // tail: tile 7 (buffer 1)
        bf16x8 af0 = *(const bf16x8*)&Al[1][wave * 16 + nn][quad * 8];
        bf16x8 af1 = *(const bf16x8*)&Al[1][wave * 16 + nn][32 + quad * 8];
#pragma unroll
        for (int nt = 0; nt < 4; nt++) {
            bf16x8 b0 = *(const bf16x8*)&Bl[1][nt * 16 + nn][quad * 8];
            bf16x8 b1 = *(const bf16x8*)&Bl[1][nt * 16 + nn][32 + quad * 8];
            acc[nt] = __builtin_amdgcn_mfma_f32_16x16x32_bf16(af0, b0, acc[nt], 0, 0, 0);
            acc[nt] = __builtin_amdgcn_mfma_f32_16x16x32_bf16(af1, b1, acc[nt], 0, 0, 0);
        }
    }
    // epilogue (identical to r7)
    int row0 = mb * 64 + wave * 16 + quad * 4;
    int col0 = nb * 64 + nn;
    int f0i = wave * 16 + quad * 4;
#pragma unroll
    for (int nt = 0; nt < 4; nt++) {
        float s = 0.f, d = 0.f;
#pragma unroll
        for (int rr = 0; rr < 4; rr++) {
            float v = acc[nt][rr];
            WhT[(unsigned)((row0 + rr) * 4096 + col0 + nt * 16)] = f2bf(v);
            s += v * asrc[f0i + rr];
            d += v * adst[f0i + rr];
        }
        s += __shfl_xor(s, 16); s += __shfl_xor(s, 32);
        d += __shfl_xor(d, 16); d += __shfl_xor(d, 32);
        if (quad == 0) { sred[0][wave][nt * 16 + nn] = s; sred[1][wave][nt * 16 + nn] = d; }
    }
    __syncthreads();
    if (tid < 64) {
        float s = sred[0][0][tid] + sred[0][1][tid] + sred[0][2][tid] + sred[0][3][tid];
        unsigned idx = mb * 4096 + nb * 64 + tid;
        expA[idx] = __builtin_amdgcn_exp2f(s);
        expC[idx] = __builtin_amdgcn_exp2f(0.2f * s);
    } else if (tid < 128) {
        int c = tid - 64;
        float d = sred[1][0][c] + sred[1][1][c] + sred[1][2][c] + sred[1][3][c];
        unsigned idx = mb * 4096 + nb * 64 + c;
        expB[idx] = __builtin_amdgcn_exp2f(d);
        expD[idx] = __builtin_amdgcn_exp2f(0.2f * d);
    }
}

// -------- kernel 3: fused masked-softmax attention + P@V + ELU (r7 + B/D prefetch) ---
__global__ __launch_bounds__(512, 4) void gat_attn(const int* __restrict__ adj,
                                                   const ushort_t* __restrict__ WhT,
                                                   const float* __restrict__ expA,
                                                   const float* __restrict__ expC,
                                                   const float* __restrict__ expB,
                                                   const float* __restrict__ expD,
                                                   float* __restrict__ out) {
    __shared__ __align__(16) ushort_t Vb[2][128][72];     // 36864 B
    __shared__ __align__(16) ushort_t Pb[2][2][32][72];   // 18432 B
    __shared__ float denoml[2][32];
    int tid = threadIdx.x;
    int wave = tid >> 6, lane = tid & 63, quad = lane >> 4, nn = lane & 15;
    int hb = blockIdx.x >> 7, ib = blockIdx.x & 127;   // adj row-band stays on one XCD
    int i0 = ib * 32;
    // gen role: (hh, pi, jo) -> 8 consecutive j per iter
    int hh = tid >> 8, tt = tid & 255;
    int pi = tt >> 3, jo = tt & 7;
    int head = hb * 2 + hh;
    float Ai = expA[head * 4096 + i0 + pi];
    float Ci = expC[head * 4096 + i0 + pi];
    const int* adjP = adj + (unsigned)(i0 + pi) * 4096 + jo * 8;
    const float* Bp = expB + (unsigned)head * 4096 + jo * 8;
    const float* Dp = expD + (unsigned)head * 4096 + jo * 8;
    // V staging role
    int vr = tid >> 3, vcs = tid & 7;
    const ushort_t* Vg0 = WhT + (unsigned)(hb * 128 + vr) * 4096 + vcs * 8;
    const ushort_t* Vg1 = Vg0 + 64u * 4096u;
    // MFMA role
    int jhalf = wave >> 2, ws = wave & 3;
    int strip = ws & 1, whead = ws >> 1;
    f32x4 acc[4] = {};
    float dpart = 0.f;
    // prologue: prefetch tile 0 (adj, B/D, V)
    int4 pa[2][2]; bf16x8 pvv[2][2]; float4 pBD[2][4];
    pa[0][0] = *(const int4*)(adjP);
    pa[0][1] = *(const int4*)(adjP + 4);
    pvv[0][0] = *(const bf16x8*)(Vg0);
    pvv[0][1] = *(const bf16x8*)(Vg1);
    pBD[0][0] = *(const float4*)(Bp);
    pBD[0][1] = *(const float4*)(Bp + 4);
    pBD[0][2] = *(const float4*)(Dp);
    pBD[0][3] = *(const float4*)(Dp + 4);
#pragma unroll 2
    for (int k = 0; k < 64; k++) {
        int cb = k & 1;
        // ---- gen tile k: w = max(Ai*B, Ci*D), masked, truncated to bf16 ----
        float4 Bv0 = pBD[cb][0], Bv1 = pBD[cb][1];
        float4 Dv0 = pBD[cb][2], Dv1 = pBD[cb][3];
        int4 a0 = pa[cb][0], a1 = pa[cb][1];
        unsigned w0, w1, w2, w3, w4, w5, w6, w7;
        {
            float w;
            w = fmaxf(Ai * Bv0.x, Ci * Dv0.x);
            w0 = __builtin_bit_cast(unsigned, w) & 0xFFFF0000u;  w0 = a0.x > 0 ? w0 : 0u;
            w = fmaxf(Ai * Bv0.y, Ci * Dv0.y);
            w1 = __builtin_bit_cast(unsigned, w) & 0xFFFF0000u;  w1 = a0.y > 0 ? w1 : 0u;
            w = fmaxf(Ai * Bv0.z, Ci * Dv0.z);
            w2 = __builtin_bit_cast(unsigned, w) & 0xFFFF0000u;  w2 = a0.z > 0 ? w2 : 0u;
            w = fmaxf(Ai * Bv0.w, Ci * Dv0.w);
            w3 = __builtin_bit_cast(unsigned, w) & 0xFFFF0000u;  w3 = a0.w > 0 ? w3 : 0u;
            w = fmaxf(Ai * Bv1.x, Ci * Dv1.x);
            w4 = __builtin_bit_cast(unsigned, w) & 0xFFFF0000u;  w4 = a1.x > 0 ? w4 : 0u;
            w = fmaxf(Ai * Bv1.y, Ci * Dv1.y);
            w5 = __builtin_bit_cast(unsigned, w) & 0xFFFF0000u;  w5 = a1.y > 0 ? w5 : 0u;
            w = fmaxf(Ai * Bv1.z, Ci * Dv1.z);
            w6 = __builtin_bit_cast(unsigned, w) & 0xFFFF0000u;  w6 = a1.z > 0 ? w6 : 0u;
            w = fmaxf(Ai * Bv1.w, Ci * Dv1.w);
            w7 = __builtin_bit_cast(unsigned, w) & 0xFFFF0000u;  w7 = a1.w > 0 ? w7 : 0u;
        }
        dpart += __builtin_bit_cast(float, w0) + __builtin_bit_cast(float, w1)
               + __builtin_bit_cast(float, w2) + __builtin_bit_cast(float, w3)
               + __builtin_bit_cast(float, w4) + __builtin_bit_cast(float, w5)
               + __builtin_bit_cast(float, w6) + __builtin_bit_cast(float, w7);
        uint4 pq;
        pq.x = __builtin_amdgcn_perm(w1, w0, 0x07060302u);
        pq.y = __builtin_amdgcn_perm(w3, w2, 0x07060302u);
        pq.z = __builtin_amdgcn_perm(w5, w4, 0x07060302u);
        pq.w = __builtin_amdgcn_perm(w7, w6, 0x07060302u);
        *(uint4*)&Pb[cb][hh][pi][jo * 8] = pq;
        *(bf16x8*)&Vb[cb][vr][vcs * 8] = pvv[cb][0];
        *(bf16x8*)&Vb[cb][64 + vr][vcs * 8] = pvv[cb][1];
        // ---- prefetch tile k+1 ----
        if (k < 63) {
            const int* ap = adjP + (k + 1) * 64;
            pa[cb ^ 1][0] = *(const int4*)(ap);
            pa[cb ^ 1][1] = *(const int4*)(ap + 4);
            pBD[cb ^ 1][0] = *(const float4*)(Bp + (k + 1) * 64);
            pBD[cb ^ 1][1] = *(const float4*)(Bp + (k + 1) * 64 + 4);
            pBD[cb ^ 1][2] = *(const float4*)(Dp + (k + 1) * 64);
            pBD[cb ^ 1][3] = *(const float4*)(Dp + (k + 1) * 64 + 4);
            pvv[cb ^ 1][0] = *(const bf16x8*)(Vg0 + (k + 1) * 64);
            pvv[cb ^ 1][1] = *(const bf16x8*)(Vg1 + (k + 1) * 64);
        }
        // ---- MFMA tile k-1 from the other buffer ----
        if (k > 0) {
            int pbuf = cb ^ 1;
            bf16x8 af = *(const bf16x8*)&Pb[pbuf][whead][strip * 16 + nn][jhalf * 32 + quad * 8];
#pragma unroll
            for (int nt = 0; nt < 4; nt++) {
                bf16x8 bv = *(const bf16x8*)&Vb[pbuf][whead * 64 + nt * 16 + nn][jhalf * 32 + quad * 8];
                acc[nt] = __builtin_amdgcn_mfma_f32_16x16x32_bf16(af, bv, acc[nt], 0, 0, 0);
            }
        }
        __syncthreads();   // BOTTOM barrier: protects next-iter overwrite AND the tail
    }
    {   // tail: mfma tile 63 (buffer 1)
        bf16x8 af = *(const bf16x8*)&Pb[1][whead][strip * 16 + nn][jhalf * 32 + quad * 8];
#pragma unroll
        for (int nt = 0; nt < 4; nt++) {
            bf16x8 bv = *(const bf16x8*)&Vb[1][whead * 64 + nt * 16 + nn][jhalf * 32 + quad * 8];
            acc[nt] = __builtin_amdgcn_mfma_f32_16x16x32_bf16(af, bv, acc[nt], 0, 0, 0);
        }
    }
    // denominator: reduce over jo (8 consecutive lanes)
    float dsum = dpart;
    dsum += __shfl_xor(dsum, 1);
    dsum += __shfl_xor(dsum, 2);
    dsum += __shfl_xor(dsum, 4);
    if ((tid & 7) == 0) denoml[hh][pi] = dsum;
    __syncthreads();   // denoml visible; tail Vb[1] reads done (cmb overlays Vb[0])
    // combine jhalf partials via LDS overlay on Vb[0] slab
    float (*cmb)[64][8] = reinterpret_cast<float (*)[64][8]>(&Vb[0][0][0]);
    if (jhalf == 1) {
        *(f32x4*)&cmb[ws][lane][0] = acc[0];
        *(f32x4*)&cmb[ws][lane][4] = acc[1];
    }
    __syncthreads();
    if (jhalf == 0) {
        f32x4 o0 = acc[0] + *(const f32x4*)&cmb[ws][lane][0];
        f32x4 o1 = acc[1] + *(const f32x4*)&cmb[ws][lane][4];
#pragma unroll
        for (int rr = 0; rr < 4; rr++) {
            int il = strip * 16 + quad * 4 + rr;
            float dnm = fmaxf(denoml[whead][il], 1e-30f);
            float v0 = o0[rr] / dnm;
            float v1 = o1[rr] / dnm;
            v0 = v0 > 0.f ? v0 : __expf(v0) - 1.f;
            v1 = v1 > 0.f ? v1 : __expf(v1) - 1.f;
            unsigned oi = (unsigned)(i0 + il) * 512 + hb * 128 + whead * 64 + nn;
            out[oi] = v0;
            out[oi + 16] = v1;
        }
    }
    __syncthreads();
    // second half: nt = 2,3 (reuse the same cmb slab)
    if (jhalf == 1) {
        *(f32x4*)&cmb[ws][lane][0] = acc[2];
        *(f32x4*)&cmb[ws][lane][4] = acc[3];
    }
    __syncthreads();
    if (jhalf == 0) {
        f32x4 o0 = acc[2] + *(const f32x4*)&cmb[ws][lane][0];
        f32x4 o1 = acc[3] + *(const f32x4*)&cmb[ws][lane][4];
#pragma unroll
        for (int rr = 0; rr < 4; rr++) {
            int il = strip * 16 + quad * 4 + rr;
            float dnm = fmaxf(denoml[whead][il], 1e-30f);
            float v0 = o0[rr] / dnm;
            float v1 = o1[rr] / dnm;
            v0 = v0 > 0.f ? v0 : __expf(v0) - 1.f;
            v1 = v1 > 0.f ? v1 : __expf(v1) - 1.f;
            unsigned oi = (unsigned)(i0 + il) * 512 + hb * 128 + whead * 64 + 32 + nn;
            out[oi] = v0;
            out[oi + 16] = v1;
        }
    }
}

extern "C" void kernel_launch(void* const* d_in, const int* in_sizes, int n_in,
                              void* d_out, int out_size, void* d_ws, size_t ws_size,
                              hipStream_t stream) {
    const float* h   = (const float*)d_in[0];   // 4096 x 512 fp32
    const int*   adj = (const int*)d_in[1];     // 4096 x 4096 int32
    const float* W   = (const float*)d_in[2];   // 512 x 512 fp32
    const float* a   = (const float*)d_in[3];   // 128 fp32

    char* ws = (char*)d_ws;
    ushort_t* WhT = (ushort_t*)ws;                      // 4 MB
    ushort_t* WT  = (ushort_t*)(ws + (4u << 20));       // 512 KB
    float* expA = (float*)(ws + (4u << 20) + (512u << 10));  // 4 x 128 KB
    float* expC = expA + 8 * 4096;
    float* expB = expC + 8 * 4096;
    float* expD = expB + 8 * 4096;

    transpose_w<<<256, 256, 0, stream>>>(W, WT);
    gemm_whT<<<512, 256, 0, stream>>>(WT, h, a, WhT, expA, expC, expB, expD);
    gat_attn<<<512, 512, 0, stream>>>(adj, WhT, expA, expC, expB, expD,
                                      (float*)d_out);
}